// Round 5
// baseline (1000.175 us; speedup 1.0000x reference)
//
#include <hip/hip_runtime.h>
#include <stdint.h>
#include <math.h>

#define NEG_INF (-__builtin_inff())
#define IDX_SENT 0x7fffffff

// ---------------------------------------------------------------------------
// JAX threefry2x32 (20 rounds), exact replication.
// ---------------------------------------------------------------------------
__device__ __forceinline__ void threefry2x32(uint32_t k0, uint32_t k1,
                                             uint32_t x0, uint32_t x1,
                                             uint32_t* o0, uint32_t* o1) {
  const uint32_t ks2 = k0 ^ k1 ^ 0x1BD11BDAu;
  uint32_t ks[3] = {k0, k1, ks2};
  const int rot[2][4] = {{13, 15, 26, 6}, {17, 29, 16, 24}};
  x0 += ks[0];
  x1 += ks[1];
#pragma unroll
  for (int i = 0; i < 5; ++i) {
#pragma unroll
    for (int j = 0; j < 4; ++j) {
      const int r = rot[i & 1][j];
      x0 += x1;
      x1 = (x1 << r) | (x1 >> (32 - r));
      x1 ^= x0;
    }
    x0 += ks[(i + 1) % 3];
    x1 += ks[(i + 2) % 3] + (uint32_t)(i + 1);
  }
  *o0 = x0;
  *o1 = x1;
}

__device__ __forceinline__ float bits_to_uniform(uint32_t bits) {
  return __uint_as_float((bits >> 9) | 0x3f800000u) - 1.0f;
}

// top3 ordered by (value desc, index asc) — matches jax.lax.top_k tie-break.
__device__ __forceinline__ void top3_insert(float v, int idx, float tv[3], int ti[3]) {
  if ((v > tv[2]) || (v == tv[2] && idx < ti[2])) {
    tv[2] = v; ti[2] = idx;
    if ((tv[2] > tv[1]) || (tv[2] == tv[1] && ti[2] < ti[1])) {
      float fv = tv[1]; int fi = ti[1];
      tv[1] = tv[2]; ti[1] = ti[2];
      tv[2] = fv;     ti[2] = fi;
      if ((tv[1] > tv[0]) || (tv[1] == tv[0] && ti[1] < ti[0])) {
        fv = tv[0]; fi = ti[0];
        tv[0] = tv[1]; ti[0] = ti[1];
        tv[1] = fv;    ti[1] = fi;
      }
    }
  }
}

// ---------------------------------------------------------------------------
// Weight transpose: w[oc][IC][3][3] -> wt[(ic*9+k)][64].
// ---------------------------------------------------------------------------
__global__ __launch_bounds__(256) void transpose_w4(
    const float* __restrict__ w, float* __restrict__ wt, int IC9) {
  const int idx = blockIdx.x * 256 + threadIdx.x;   // qrow*64 + oc
  const int qrow = idx >> 6;
  const int oc = idx & 63;
  const float4 v = *(const float4*)&w[(size_t)oc * IC9 + qrow * 4];
  wt[(size_t)(qrow * 4 + 0) * 64 + oc] = v.x;
  wt[(size_t)(qrow * 4 + 1) * 64 + oc] = v.y;
  wt[(size_t)(qrow * 4 + 2) * 64 + oc] = v.z;
  wt[(size_t)(qrow * 4 + 3) * 64 + oc] = v.w;
}

// ---------------------------------------------------------------------------
// conv3x3 (pad 1) + inference BN + ReLU.  x:[32,IC,64,64] wt:[(IC*9)][64]
// out:[32,64,64,64].
// Grid: 32 batches x 16 tiles (16x16) x 2 oc-halves = 1024 blocks (4/CU).
// Block: 256 threads = 8 oc-groups x 32 pixel-groups; thread: 8px x 4oc.
// Weights are NOT staged in LDS: per (ic,tap) a wave's 8 oc-groups read one
// contiguous 128B line from L2 (reused by all 1024 blocks) — halves LDS-pipe
// demand vs round-3 (the measured 58% VALUBusy limiter).
// Accumulation order identical to rounds 1-3 (bit-identical output).
// ---------------------------------------------------------------------------
template <int IC>
__global__ __launch_bounds__(256, 4) void conv3x3_bn_relu(
    const float* __restrict__ x, const float* __restrict__ wt,
    const float* __restrict__ g, const float* __restrict__ bb,
    const float* __restrict__ m, const float* __restrict__ vv,
    float* __restrict__ out) {
  __shared__ float xs[8][18][20];   // 8 ic x 18 halo rows x 20 cols (16B align)

  const int tid = threadIdx.x;
  const int blk = blockIdx.x;
  const int b = blk >> 5;
  const int tile = (blk >> 1) & 15;
  const int och = blk & 1;
  const int by = (tile >> 2) << 4;
  const int bx = (tile & 3) << 4;
  const int ocg = tid & 7;           // oc_local = ocg*4 + j
  const int pg = tid >> 3;
  const int pr = pg >> 1;
  const int pc = (pg & 1) << 3;

  // input staging decomposition (division-free)
  const int sic = tid >> 5;          // 0..7
  const int sc = tid & 31;           // cols 0..17 active
  const int gx = bx + sc - 1;
  const bool cok = (sc < 18) && (gx >= 0) && (gx < 64);

  // weight quad pointer: wt row = 16 float4; this thread's quad column:
  const float4* wquad = (const float4*)wt + (och << 3) + ocg;

  float acc[8][4];
#pragma unroll
  for (int p = 0; p < 8; ++p)
#pragma unroll
    for (int j = 0; j < 4; ++j) acc[p][j] = 0.0f;

  for (int icb = 0; icb < IC; icb += 8) {
    // ---- stage input tile (zero halo), 18 predicated rows ----
    const float* xp = x + ((size_t)b * IC + icb + sic) * 4096;
#pragma unroll
    for (int r = 0; r < 18; ++r) {
      const int gy = by + r - 1;
      float val = 0.0f;
      if (cok && gy >= 0 && gy < 64) val = xp[gy * 64 + gx];
      if (sc < 18) xs[sic][r][sc] = val;
    }
    __syncthreads();

    const float4* wb = wquad + (size_t)icb * 9 * 16;
    for (int ic = 0; ic < 8; ++ic) {
      // 9 weight quads straight from L2 (no LDS round-trip)
      float4 wq[9];
#pragma unroll
      for (int k = 0; k < 9; ++k) wq[k] = wb[(ic * 9 + k) * 16];

#pragma unroll
      for (int ky = 0; ky < 3; ++ky) {
        const float* row = &xs[ic][pr + ky][pc];   // 16B aligned
        float xv[10];
        *(float4*)&xv[0] = *(const float4*)&row[0];
        *(float4*)&xv[4] = *(const float4*)&row[4];
        *(float2*)&xv[8] = *(const float2*)&row[8];
#pragma unroll
        for (int kx = 0; kx < 3; ++kx) {
          const float4 w4 = wq[ky * 3 + kx];
#pragma unroll
          for (int p = 0; p < 8; ++p) {
            acc[p][0] = fmaf(xv[p + kx], w4.x, acc[p][0]);
            acc[p][1] = fmaf(xv[p + kx], w4.y, acc[p][1]);
            acc[p][2] = fmaf(xv[p + kx], w4.z, acc[p][2]);
            acc[p][3] = fmaf(xv[p + kx], w4.w, acc[p][3]);
          }
        }
      }
    }
    __syncthreads();
  }

  // ---- epilogue: BN + ReLU + store ----
#pragma unroll
  for (int j = 0; j < 4; ++j) {
    const int oc = (och << 5) + (ocg << 2) + j;
    const float sc2 = g[oc] * (1.0f / sqrtf(vv[oc] + 1e-5f));
    const float sh = bb[oc] - m[oc] * sc2;
#pragma unroll
    for (int p = 0; p < 8; ++p) {
      float o = fmaf(acc[p][j], sc2, sh);
      o = fmaxf(o, 0.0f);
      out[(((size_t)b * 64 + oc) * 64 + (by + pr)) * 64 + (bx + pc + p)] = o;
    }
  }
}

// ---------------------------------------------------------------------------
// 1x1 conv (64->1) + bias into lg64[32][4096].  Grid 32*16 blocks.
// ---------------------------------------------------------------------------
__global__ __launch_bounds__(256) void logits64_k(
    const float* __restrict__ h2, const float* __restrict__ w3,
    const float* __restrict__ b3, float* __restrict__ lg64) {
  const int blk = blockIdx.x;
  const int b = blk >> 4;
  const int p = ((blk & 15) << 8) + threadIdx.x;
  __shared__ float wv[64];
  if (threadIdx.x < 64) wv[threadIdx.x] = w3[threadIdx.x];
  __syncthreads();
  float s = b3[0];
  const float* hp = h2 + (size_t)b * 64 * 4096 + p;
  for (int oc = 0; oc < 64; ++oc)
    s = fmaf(hp[(size_t)oc * 4096], wv[oc], s);
  lg64[b * 4096 + p] = s;
}

// ---------------------------------------------------------------------------
// bilinear 64->256 (half-pixel, edge clamp) + sigmoid.
// ---------------------------------------------------------------------------
__global__ __launch_bounds__(256) void upsample_k(
    const float* __restrict__ lg64, float* __restrict__ logits,
    float* __restrict__ heat) {
  const int blk = blockIdx.x;
  const int b = blk >> 6;
  const int qq = ((blk & 63) << 10) + (threadIdx.x << 2);
  const float* lg = lg64 + b * 4096;
  const int oy = qq >> 8;
  const float sy = (float)oy * 0.25f - 0.375f;
  const float fy = floorf(sy);
  const int y0 = (int)fy;
  const float ty = sy - fy;
  const int y0c = y0 < 0 ? 0 : y0;
  const int y1c = (y0 + 1) > 63 ? 63 : (y0 + 1);
  const float* r0 = lg + y0c * 64;
  const float* r1 = lg + y1c * 64;
  float4 lo, he;
  float* lop = (float*)&lo;
  float* hep = (float*)&he;
#pragma unroll
  for (int j = 0; j < 4; ++j) {
    const int ox = (qq & 255) + j;
    const float sx = (float)ox * 0.25f - 0.375f;
    const float fx = floorf(sx);
    const int x0 = (int)fx;
    const float tx = sx - fx;
    const int x0c = x0 < 0 ? 0 : x0;
    const int x1c = (x0 + 1) > 63 ? 63 : (x0 + 1);
    const float v00 = r0[x0c], v01 = r0[x1c];
    const float v10 = r1[x0c], v11 = r1[x1c];
    const float vtop = v00 + (v01 - v00) * tx;
    const float vbot = v10 + (v11 - v10) * tx;
    const float val = vtop + (vbot - vtop) * ty;
    lop[j] = val;
    hep[j] = 1.0f / (1.0f + expf(-val));
  }
  const size_t o = (size_t)b * 65536 + qq;
  *(float4*)(logits + o) = lo;
  *(float4*)(heat + o) = he;
}

// ---------------------------------------------------------------------------
// Positive points, phase 1: per-stripe 9x9 NMS peak top3 + stripe argmax.
// ---------------------------------------------------------------------------
__global__ __launch_bounds__(256) void pos_stripe(
    const float* __restrict__ heat, float* __restrict__ cand) {
  const int b = blockIdx.x >> 4;
  const int stripe = blockIdx.x & 15;
  const int y0 = stripe << 4;
  const float* s = heat + (size_t)b * 65536;
  const int tid = threadIdx.x;
  __shared__ float sm[24][256];
  __shared__ float rm[24][256];
  __shared__ float rv[256 * 3];
  __shared__ int ri[256 * 3];
  __shared__ float mvv[256];
  __shared__ int mii[256];
  __shared__ float rv2[24];
  __shared__ int ri2[24];
  __shared__ float mv2[8];
  __shared__ int mi2[8];

  for (int l = tid; l < 24 * 256; l += 256) {
    const int rr = l >> 8, xx = l & 255;
    const int gy = y0 - 4 + rr;
    sm[rr][xx] = (gy >= 0 && gy < 256) ? s[gy * 256 + xx] : NEG_INF;
  }
  __syncthreads();
  for (int l = tid; l < 24 * 256; l += 256) {
    const int rr = l >> 8, xx = l & 255;
    const int lo = (xx - 4 < 0) ? 0 : xx - 4;
    const int hi = (xx + 4 > 255) ? 255 : xx + 4;
    float mx = NEG_INF;
    for (int x2 = lo; x2 <= hi; ++x2) mx = fmaxf(mx, sm[rr][x2]);
    rm[rr][xx] = mx;
  }
  __syncthreads();

  float tv[3] = {NEG_INF, NEG_INF, NEG_INF};
  int ti[3] = {IDX_SENT, IDX_SENT, IDX_SENT};
  float bmax = NEG_INF;
  int bidx = IDX_SENT;
  for (int l = tid; l < 16 * 256; l += 256) {
    const int ry = l >> 8, xx = l & 255;
    const int lr = ry + 4;
    const float v = sm[lr][xx];
    float lm = rm[lr - 4][xx];
#pragma unroll
    for (int d = -3; d <= 4; ++d) lm = fmaxf(lm, rm[lr + d][xx]);
    const int gidx = (y0 + ry) * 256 + xx;
    if (v > bmax) { bmax = v; bidx = gidx; }
    if (v == lm && v > 0.1f) top3_insert(v, gidx, tv, ti);
  }

  rv[tid * 3 + 0] = tv[0]; rv[tid * 3 + 1] = tv[1]; rv[tid * 3 + 2] = tv[2];
  ri[tid * 3 + 0] = ti[0]; ri[tid * 3 + 1] = ti[1]; ri[tid * 3 + 2] = ti[2];
  mvv[tid] = bmax; mii[tid] = bidx;
  __syncthreads();

  if (tid < 8) {
    float av[3] = {NEG_INF, NEG_INF, NEG_INF};
    int ai[3] = {IDX_SENT, IDX_SENT, IDX_SENT};
    float am = NEG_INF; int amI = IDX_SENT;
    for (int t = tid * 32; t < tid * 32 + 32; ++t) {
      for (int k = 0; k < 3; ++k) top3_insert(rv[t * 3 + k], ri[t * 3 + k], av, ai);
      if (mvv[t] > am || (mvv[t] == am && mii[t] < amI)) { am = mvv[t]; amI = mii[t]; }
    }
    rv2[tid * 3 + 0] = av[0]; rv2[tid * 3 + 1] = av[1]; rv2[tid * 3 + 2] = av[2];
    ri2[tid * 3 + 0] = ai[0]; ri2[tid * 3 + 1] = ai[1]; ri2[tid * 3 + 2] = ai[2];
    mv2[tid] = am; mi2[tid] = amI;
  }
  __syncthreads();

  if (tid == 0) {
    float fv[3] = {NEG_INF, NEG_INF, NEG_INF};
    int fi[3] = {IDX_SENT, IDX_SENT, IDX_SENT};
    for (int t = 0; t < 24; ++t) top3_insert(rv2[t], ri2[t], fv, fi);
    float gbv = NEG_INF; int gbi = IDX_SENT;
    for (int t = 0; t < 8; ++t)
      if (mv2[t] > gbv || (mv2[t] == gbv && mi2[t] < gbi)) { gbv = mv2[t]; gbi = mi2[t]; }
    float* c = cand + ((size_t)b * 16 + stripe) * 8;
    c[0] = fv[0]; c[1] = __int_as_float(fi[0]);
    c[2] = fv[1]; c[3] = __int_as_float(fi[1]);
    c[4] = fv[2]; c[5] = __int_as_float(fi[2]);
    c[6] = gbv;   c[7] = __int_as_float(gbi);
  }
}

// ---------------------------------------------------------------------------
// Positive points, phase 2: reduce 16 stripe candidates -> final outputs.
// ---------------------------------------------------------------------------
__global__ void pos_final(const float* __restrict__ cand,
                          float* __restrict__ coords, float* __restrict__ labels) {
  const int b = blockIdx.x;
  if (threadIdx.x != 0) return;
  float fv[3] = {NEG_INF, NEG_INF, NEG_INF};
  int fi[3] = {IDX_SENT, IDX_SENT, IDX_SENT};
  float gbv = NEG_INF; int gbi = IDX_SENT;
  for (int st = 0; st < 16; ++st) {
    const float* c = cand + ((size_t)b * 16 + st) * 8;
    for (int k = 0; k < 3; ++k)
      top3_insert(c[2 * k], __float_as_int(c[2 * k + 1]), fv, fi);
    const float mv = c[6]; const int mi = __float_as_int(c[7]);
    if (mv > gbv || (mv == gbv && mi < gbi)) { gbv = mv; gbi = mi; }
  }
  float* co = coords + (size_t)b * 10;
  float* la = labels + (size_t)b * 5;
  const bool any_peak = (fi[0] != IDX_SENT);
  const int i0 = any_peak ? fi[0] : gbi;
  co[0] = (float)(i0 & 255);
  co[1] = (float)(i0 >> 8);
  la[0] = 1.0f;
  for (int k = 1; k < 3; ++k) {
    const bool valid = (fi[k] != IDX_SENT);
    co[k * 2 + 0] = valid ? (float)(fi[k] & 255) : 0.0f;
    co[k * 2 + 1] = valid ? (float)(fi[k] >> 8) : 0.0f;
    la[k] = valid ? 1.0f : -1.0f;
  }
}

// ---------------------------------------------------------------------------
// Negative points, phase 1: per-64px-chunk count of (heat<0.3) + partial max.
// ---------------------------------------------------------------------------
__global__ __launch_bounds__(256) void neg_count(
    const float* __restrict__ heat, float* __restrict__ ncnt,
    float* __restrict__ pmax) {
  const int blk = blockIdx.x;
  const int b = blk >> 2;
  const int part = blk & 3;
  const int tid = threadIdx.x;
  const int chunk = (part << 8) + tid;
  const float4* s = (const float4*)(heat + (size_t)b * 65536 + chunk * 64);
  int c = 0;
  float mx = NEG_INF;
  for (int i = 0; i < 16; ++i) {
    const float4 v = s[i];
    c += (v.x < 0.3f) + (v.y < 0.3f) + (v.z < 0.3f) + (v.w < 0.3f);
    mx = fmaxf(mx, fmaxf(fmaxf(v.x, v.y), fmaxf(v.z, v.w)));
  }
  ncnt[b * 1024 + chunk] = (float)c;
  __shared__ float mxs[256];
  mxs[tid] = mx;
  __syncthreads();
  if (tid == 0) {
    float g = NEG_INF;
    for (int t = 0; t < 256; ++t) g = fmaxf(g, mxs[t]);
    pmax[blk] = g;
  }
}

// ---------------------------------------------------------------------------
// Negative points, phase 2: prefix, PRNG rank select, rescan.
// ---------------------------------------------------------------------------
__global__ __launch_bounds__(256) void neg_select(
    const float* __restrict__ heat, const float* __restrict__ ncnt,
    const float* __restrict__ pmax, float* __restrict__ coords,
    float* __restrict__ labels) {
  const int b = blockIdx.x;
  const int tid = threadIdx.x;
  const float* s = heat + (size_t)b * 65536;
  __shared__ float cnt[1024];
  __shared__ float c256[256];
  __shared__ int pfx[257];
  __shared__ float thr_s;
  __shared__ int fb_s;
  __shared__ int n_s;
  __shared__ int ridx_s[2];

  for (int l = tid; l < 1024; l += 256) cnt[l] = ncnt[b * 1024 + l];
  __syncthreads();
  c256[tid] = cnt[4 * tid] + cnt[4 * tid + 1] + cnt[4 * tid + 2] + cnt[4 * tid + 3];
  __syncthreads();
  if (tid == 0) {
    int tot = 0;
    for (int t = 0; t < 256; ++t) tot += (int)c256[t];
    const float gm = fmaxf(fmaxf(pmax[b * 4], pmax[b * 4 + 1]),
                           fmaxf(pmax[b * 4 + 2], pmax[b * 4 + 3]));
    fb_s = (tot > 0) ? 0 : 1;
    thr_s = (tot > 0) ? 0.3f : gm;
  }
  __syncthreads();
  if (fb_s) {
    const float t2 = thr_s;
    const int base = tid * 256;
    int c = 0;
    for (int i = 0; i < 256; ++i) c += (s[base + i] < t2) ? 1 : 0;
    c256[tid] = (float)c;
    __syncthreads();
  }
  if (tid == 0) {
    int run = 0;
    for (int t = 0; t < 256; ++t) { pfx[t] = run; run += (int)c256[t]; }
    pfx[256] = run;
    const int n = run;
    n_s = n;
    uint32_t k0, k1, a0, a1;
    threefry2x32(0u, 42u, 0u, (uint32_t)b, &k0, &k1);
    threefry2x32(k0, k1, 0u, 0u, &a0, &a1);
    const uint32_t bits0 = a0 ^ a1;
    threefry2x32(k0, k1, 0u, 1u, &a0, &a1);
    const uint32_t bits1 = a0 ^ a1;
    const float u0 = bits_to_uniform(bits0);
    const float u1 = bits_to_uniform(bits1);
    const float nf = (float)(n > 1 ? n : 1);
    int r0 = (int)(u0 * nf);
    int r1 = (int)(u1 * nf);
    const int rmax = (n - 1 > 0) ? n - 1 : 0;
    ridx_s[0] = r0 < rmax ? r0 : rmax;
    ridx_s[1] = r1 < rmax ? r1 : rmax;
    labels[(size_t)b * 5 + 3] = 0.0f;
    labels[(size_t)b * 5 + 4] = 0.0f;
    if (n == 0) {
      coords[(size_t)b * 10 + 6] = 0.0f; coords[(size_t)b * 10 + 7] = 0.0f;
      coords[(size_t)b * 10 + 8] = 0.0f; coords[(size_t)b * 10 + 9] = 0.0f;
    }
  }
  __syncthreads();
  const int n = n_s;
  if (n > 0) {
    const float t2 = thr_s;
    const int p0 = pfx[tid], p1 = pfx[tid + 1];
    const int base = tid * 256;
    for (int j = 0; j < 2; ++j) {
      const int r = ridx_s[j];
      if (r >= p0 && r < p1) {
        int need = r - p0;
        int sel = -1;
        for (int i = 0; i < 256; ++i) {
          if (s[base + i] < t2) {
            if (need == 0) { sel = base + i; break; }
            --need;
          }
        }
        coords[(size_t)b * 10 + 6 + j * 2 + 0] = (float)(sel & 255);
        coords[(size_t)b * 10 + 6 + j * 2 + 1] = (float)(sel >> 8);
      }
    }
  }
}

// ---------------------------------------------------------------------------
extern "C" void kernel_launch(void* const* d_in, const int* in_sizes, int n_in,
                              void* d_out, int out_size, void* d_ws, size_t ws_size,
                              hipStream_t stream) {
  (void)in_sizes; (void)n_in; (void)out_size; (void)ws_size;
  const float* x  = (const float*)d_in[0];
  const float* w1 = (const float*)d_in[1];
  const float* g1 = (const float*)d_in[2];
  const float* b1 = (const float*)d_in[3];
  const float* m1 = (const float*)d_in[4];
  const float* v1 = (const float*)d_in[5];
  const float* w2 = (const float*)d_in[6];
  const float* g2 = (const float*)d_in[7];
  const float* b2 = (const float*)d_in[8];
  const float* m2 = (const float*)d_in[9];
  const float* v2 = (const float*)d_in[10];
  const float* w3 = (const float*)d_in[11];
  const float* b3 = (const float*)d_in[12];

  float* out = (float*)d_out;
  float* heat = out;                         // [32,1,256,256]
  float* coords = out + (size_t)32 * 65536;  // [32,1,5,2]
  float* labels = coords + 320;              // [32,1,5]
  float* logits = labels + 160;              // [32,1,256,256]

  // Transposed weights live in the logits region (overwritten by upsample_k
  // only after both convs have consumed them — stream-ordered, no hazard).
  float* w1t = logits;            // 256*9*64 floats
  float* w2t = logits + 147456;   // 64*9*64 floats

  float* h1 = (float*)d_ws;                        // [32,64,64,64]
  float* h2 = h1 + (size_t)32 * 64 * 64 * 64;      // [32,64,64,64]
  float* lg64 = h1;                                // reuse after conv2
  float* cand = h1 + 131072;
  float* ncnt = h1 + 135168;
  float* pmax = h1 + 167936;

  transpose_w4<<<144, 256, 0, stream>>>(w1, w1t, 2304);
  transpose_w4<<<36, 256, 0, stream>>>(w2, w2t, 576);
  conv3x3_bn_relu<256><<<1024, 256, 0, stream>>>(x, w1t, g1, b1, m1, v1, h1);
  conv3x3_bn_relu<64><<<1024, 256, 0, stream>>>(h1, w2t, g2, b2, m2, v2, h2);
  logits64_k<<<512, 256, 0, stream>>>(h2, w3, b3, lg64);
  upsample_k<<<2048, 256, 0, stream>>>(lg64, logits, heat);
  pos_stripe<<<512, 256, 0, stream>>>(heat, cand);
  pos_final<<<32, 64, 0, stream>>>(cand, coords, labels);
  neg_count<<<128, 256, 0, stream>>>(heat, ncnt, pmax);
  neg_select<<<32, 256, 0, stream>>>(heat, ncnt, pmax, coords, labels);
}

// Round 6
// 826.288 us; speedup vs baseline: 1.2104x; 1.2104x over previous
//
#include <hip/hip_runtime.h>
#include <stdint.h>
#include <math.h>

#define NEG_INF (-__builtin_inff())
#define IDX_SENT 0x7fffffff

// ---------------------------------------------------------------------------
// JAX threefry2x32 (20 rounds), exact replication.
// ---------------------------------------------------------------------------
__device__ __forceinline__ void threefry2x32(uint32_t k0, uint32_t k1,
                                             uint32_t x0, uint32_t x1,
                                             uint32_t* o0, uint32_t* o1) {
  const uint32_t ks2 = k0 ^ k1 ^ 0x1BD11BDAu;
  uint32_t ks[3] = {k0, k1, ks2};
  const int rot[2][4] = {{13, 15, 26, 6}, {17, 29, 16, 24}};
  x0 += ks[0];
  x1 += ks[1];
#pragma unroll
  for (int i = 0; i < 5; ++i) {
#pragma unroll
    for (int j = 0; j < 4; ++j) {
      const int r = rot[i & 1][j];
      x0 += x1;
      x1 = (x1 << r) | (x1 >> (32 - r));
      x1 ^= x0;
    }
    x0 += ks[(i + 1) % 3];
    x1 += ks[(i + 2) % 3] + (uint32_t)(i + 1);
  }
  *o0 = x0;
  *o1 = x1;
}

__device__ __forceinline__ float bits_to_uniform(uint32_t bits) {
  return __uint_as_float((bits >> 9) | 0x3f800000u) - 1.0f;
}

// top3 ordered by (value desc, index asc) — matches jax.lax.top_k tie-break.
__device__ __forceinline__ void top3_insert(float v, int idx, float tv[3], int ti[3]) {
  if ((v > tv[2]) || (v == tv[2] && idx < ti[2])) {
    tv[2] = v; ti[2] = idx;
    if ((tv[2] > tv[1]) || (tv[2] == tv[1] && ti[2] < ti[1])) {
      float fv = tv[1]; int fi = ti[1];
      tv[1] = tv[2]; ti[1] = ti[2];
      tv[2] = fv;     ti[2] = fi;
      if ((tv[1] > tv[0]) || (tv[1] == tv[0] && ti[1] < ti[0])) {
        fv = tv[0]; fi = ti[0];
        tv[0] = tv[1]; ti[0] = ti[1];
        tv[1] = fv;    ti[1] = fi;
      }
    }
  }
}

// ---------------------------------------------------------------------------
// Weight transpose: w[oc][IC][3][3] -> wt[(ic*9+k)][64].
// ---------------------------------------------------------------------------
__global__ __launch_bounds__(256) void transpose_w4(
    const float* __restrict__ w, float* __restrict__ wt, int IC9) {
  const int idx = blockIdx.x * 256 + threadIdx.x;   // qrow*64 + oc
  const int qrow = idx >> 6;
  const int oc = idx & 63;
  const float4 v = *(const float4*)&w[(size_t)oc * IC9 + qrow * 4];
  wt[(size_t)(qrow * 4 + 0) * 64 + oc] = v.x;
  wt[(size_t)(qrow * 4 + 1) * 64 + oc] = v.y;
  wt[(size_t)(qrow * 4 + 2) * 64 + oc] = v.z;
  wt[(size_t)(qrow * 4 + 3) * 64 + oc] = v.w;
}

// ---------------------------------------------------------------------------
// conv3x3 (pad 1) + inference BN + ReLU.  x:[32,IC,64,64] wt:[(IC*9)][64]
// out:[32,64,64,64].
// Grid: 32 batches x 32 tiles (8 rows x 16 cols) = 1024 blocks (4/CU).
// Block: 4 waves; wave w owns ocs [16w,16w+16) — WAVE-UNIFORM, so weight
// addresses are scalar: the compiler emits s_load_dwordx16 (SMEM pipe) and
// v_fma with SGPR operand — weights cost zero LDS/VMEM-vector traffic.
// Lane: (row r 0..7, colpair cg 0..7) -> 2 px x 16 oc = 32 acc VGPRs.
// Per ic per lane: 6 aligned ds_read_b64 (bank-balanced) serve 288 FMAs
// (LDS:VALU ratio ~0.33 vs round-3's 1.5 — the measured limiter).
// Accumulation order per output element: (icb, ic, ky, kx) — identical to
// rounds 1-5 => bit-identical numerics.
// ---------------------------------------------------------------------------
template <int IC>
__global__ __launch_bounds__(256, 4) void conv3x3_bn_relu(
    const float* __restrict__ x, const float* __restrict__ wt,
    const float* __restrict__ g, const float* __restrict__ bb,
    const float* __restrict__ m, const float* __restrict__ vv,
    float* __restrict__ out) {
  __shared__ float xs[8][10][20];   // 8 ic x 10 halo rows x 20 cols (8B align)

  const int tid = threadIdx.x;
  const int blk = blockIdx.x;
  const int b = blk >> 5;
  const int tile = blk & 31;
  const int by = (tile >> 2) << 3;   // 8-row tile
  const int bx = (tile & 3) << 4;    // 16-col tile
  const int wv = __builtin_amdgcn_readfirstlane(tid >> 6);  // wave id 0..3
  const int lane = tid & 63;
  const int r = lane >> 3;           // 0..7 output row in tile
  const int lc = (lane & 7) << 1;    // 0,2,..,14 col base (2 px)
  const int ocbase = wv << 4;        // wave-uniform oc base

  // input staging decomposition (division-free)
  const int sic = tid >> 5;          // 0..7
  const int sc = tid & 31;           // cols 0..17 active
  const int gx = bx + sc - 1;
  const bool cok = (sc < 18) && (gx >= 0) && (gx < 64);

  float acc[2][16];
#pragma unroll
  for (int p = 0; p < 2; ++p)
#pragma unroll
    for (int o = 0; o < 16; ++o) acc[p][o] = 0.0f;

  for (int icb = 0; icb < IC; icb += 8) {
    // ---- stage input tile (zero halo), 10 predicated rows ----
    const float* xp = x + ((size_t)b * IC + icb + sic) * 4096;
#pragma unroll
    for (int rr = 0; rr < 10; ++rr) {
      const int gy = by + rr - 1;
      float val = 0.0f;
      if (cok && gy >= 0 && gy < 64) val = xp[gy * 64 + gx];
      if (sc < 18) xs[sic][rr][sc] = val;
    }
    __syncthreads();

    const float* wbase = wt + (size_t)icb * 9 * 64 + ocbase;  // uniform
    for (int ic = 0; ic < 8; ++ic) {
#pragma unroll
      for (int ky = 0; ky < 3; ++ky) {
        float xv[4];
        *(float2*)&xv[0] = *(const float2*)&xs[ic][r + ky][lc];
        *(float2*)&xv[2] = *(const float2*)&xs[ic][r + ky][lc + 2];
#pragma unroll
        for (int kx = 0; kx < 3; ++kx) {
          // wave-uniform address -> s_load_dwordx16 into SGPRs
          const float4* wp4 = (const float4*)(wbase + (ic * 9 + ky * 3 + kx) * 64);
#pragma unroll
          for (int q = 0; q < 4; ++q) {
            const float4 w4 = wp4[q];
            acc[0][4 * q + 0] = fmaf(xv[kx],     w4.x, acc[0][4 * q + 0]);
            acc[1][4 * q + 0] = fmaf(xv[kx + 1], w4.x, acc[1][4 * q + 0]);
            acc[0][4 * q + 1] = fmaf(xv[kx],     w4.y, acc[0][4 * q + 1]);
            acc[1][4 * q + 1] = fmaf(xv[kx + 1], w4.y, acc[1][4 * q + 1]);
            acc[0][4 * q + 2] = fmaf(xv[kx],     w4.z, acc[0][4 * q + 2]);
            acc[1][4 * q + 2] = fmaf(xv[kx + 1], w4.z, acc[1][4 * q + 2]);
            acc[0][4 * q + 3] = fmaf(xv[kx],     w4.w, acc[0][4 * q + 3]);
            acc[1][4 * q + 3] = fmaf(xv[kx + 1], w4.w, acc[1][4 * q + 3]);
          }
        }
      }
    }
    __syncthreads();
  }

  // ---- epilogue: BN + ReLU + float2 store ----
#pragma unroll
  for (int o = 0; o < 16; ++o) {
    const int oc = ocbase + o;
    const float sc2 = g[oc] * (1.0f / sqrtf(vv[oc] + 1e-5f));
    const float sh = bb[oc] - m[oc] * sc2;
    float2 v;
    v.x = fmaxf(fmaf(acc[0][o], sc2, sh), 0.0f);
    v.y = fmaxf(fmaf(acc[1][o], sc2, sh), 0.0f);
    *(float2*)&out[(((size_t)b * 64 + oc) * 64 + (by + r)) * 64 + bx + lc] = v;
  }
}

// ---------------------------------------------------------------------------
// 1x1 conv (64->1) + bias into lg64[32][4096].  Grid 32*16 blocks.
// ---------------------------------------------------------------------------
__global__ __launch_bounds__(256) void logits64_k(
    const float* __restrict__ h2, const float* __restrict__ w3,
    const float* __restrict__ b3, float* __restrict__ lg64) {
  const int blk = blockIdx.x;
  const int b = blk >> 4;
  const int p = ((blk & 15) << 8) + threadIdx.x;
  __shared__ float wvv[64];
  if (threadIdx.x < 64) wvv[threadIdx.x] = w3[threadIdx.x];
  __syncthreads();
  float s = b3[0];
  const float* hp = h2 + (size_t)b * 64 * 4096 + p;
  for (int oc = 0; oc < 64; ++oc)
    s = fmaf(hp[(size_t)oc * 4096], wvv[oc], s);
  lg64[b * 4096 + p] = s;
}

// ---------------------------------------------------------------------------
// bilinear 64->256 (half-pixel, edge clamp) + sigmoid.
// ---------------------------------------------------------------------------
__global__ __launch_bounds__(256) void upsample_k(
    const float* __restrict__ lg64, float* __restrict__ logits,
    float* __restrict__ heat) {
  const int blk = blockIdx.x;
  const int b = blk >> 6;
  const int qq = ((blk & 63) << 10) + (threadIdx.x << 2);
  const float* lg = lg64 + b * 4096;
  const int oy = qq >> 8;
  const float sy = (float)oy * 0.25f - 0.375f;
  const float fy = floorf(sy);
  const int y0 = (int)fy;
  const float ty = sy - fy;
  const int y0c = y0 < 0 ? 0 : y0;
  const int y1c = (y0 + 1) > 63 ? 63 : (y0 + 1);
  const float* r0 = lg + y0c * 64;
  const float* r1 = lg + y1c * 64;
  float4 lo, he;
  float* lop = (float*)&lo;
  float* hep = (float*)&he;
#pragma unroll
  for (int j = 0; j < 4; ++j) {
    const int ox = (qq & 255) + j;
    const float sx = (float)ox * 0.25f - 0.375f;
    const float fx = floorf(sx);
    const int x0 = (int)fx;
    const float tx = sx - fx;
    const int x0c = x0 < 0 ? 0 : x0;
    const int x1c = (x0 + 1) > 63 ? 63 : (x0 + 1);
    const float v00 = r0[x0c], v01 = r0[x1c];
    const float v10 = r1[x0c], v11 = r1[x1c];
    const float vtop = v00 + (v01 - v00) * tx;
    const float vbot = v10 + (v11 - v10) * tx;
    const float val = vtop + (vbot - vtop) * ty;
    lop[j] = val;
    hep[j] = 1.0f / (1.0f + expf(-val));
  }
  const size_t o = (size_t)b * 65536 + qq;
  *(float4*)(logits + o) = lo;
  *(float4*)(heat + o) = he;
}

// ---------------------------------------------------------------------------
// Positive points, phase 1: per-stripe 9x9 NMS peak top3 + stripe argmax.
// ---------------------------------------------------------------------------
__global__ __launch_bounds__(256) void pos_stripe(
    const float* __restrict__ heat, float* __restrict__ cand) {
  const int b = blockIdx.x >> 4;
  const int stripe = blockIdx.x & 15;
  const int y0 = stripe << 4;
  const float* s = heat + (size_t)b * 65536;
  const int tid = threadIdx.x;
  __shared__ float sm[24][256];
  __shared__ float rm[24][256];
  __shared__ float rv[256 * 3];
  __shared__ int ri[256 * 3];
  __shared__ float mvv[256];
  __shared__ int mii[256];
  __shared__ float rv2[24];
  __shared__ int ri2[24];
  __shared__ float mv2[8];
  __shared__ int mi2[8];

  for (int l = tid; l < 24 * 256; l += 256) {
    const int rr = l >> 8, xx = l & 255;
    const int gy = y0 - 4 + rr;
    sm[rr][xx] = (gy >= 0 && gy < 256) ? s[gy * 256 + xx] : NEG_INF;
  }
  __syncthreads();
  for (int l = tid; l < 24 * 256; l += 256) {
    const int rr = l >> 8, xx = l & 255;
    const int lo = (xx - 4 < 0) ? 0 : xx - 4;
    const int hi = (xx + 4 > 255) ? 255 : xx + 4;
    float mx = NEG_INF;
    for (int x2 = lo; x2 <= hi; ++x2) mx = fmaxf(mx, sm[rr][x2]);
    rm[rr][xx] = mx;
  }
  __syncthreads();

  float tv[3] = {NEG_INF, NEG_INF, NEG_INF};
  int ti[3] = {IDX_SENT, IDX_SENT, IDX_SENT};
  float bmax = NEG_INF;
  int bidx = IDX_SENT;
  for (int l = tid; l < 16 * 256; l += 256) {
    const int ry = l >> 8, xx = l & 255;
    const int lr = ry + 4;
    const float v = sm[lr][xx];
    float lm = rm[lr - 4][xx];
#pragma unroll
    for (int d = -3; d <= 4; ++d) lm = fmaxf(lm, rm[lr + d][xx]);
    const int gidx = (y0 + ry) * 256 + xx;
    if (v > bmax) { bmax = v; bidx = gidx; }
    if (v == lm && v > 0.1f) top3_insert(v, gidx, tv, ti);
  }

  rv[tid * 3 + 0] = tv[0]; rv[tid * 3 + 1] = tv[1]; rv[tid * 3 + 2] = tv[2];
  ri[tid * 3 + 0] = ti[0]; ri[tid * 3 + 1] = ti[1]; ri[tid * 3 + 2] = ti[2];
  mvv[tid] = bmax; mii[tid] = bidx;
  __syncthreads();

  if (tid < 8) {
    float av[3] = {NEG_INF, NEG_INF, NEG_INF};
    int ai[3] = {IDX_SENT, IDX_SENT, IDX_SENT};
    float am = NEG_INF; int amI = IDX_SENT;
    for (int t = tid * 32; t < tid * 32 + 32; ++t) {
      for (int k = 0; k < 3; ++k) top3_insert(rv[t * 3 + k], ri[t * 3 + k], av, ai);
      if (mvv[t] > am || (mvv[t] == am && mii[t] < amI)) { am = mvv[t]; amI = mii[t]; }
    }
    rv2[tid * 3 + 0] = av[0]; rv2[tid * 3 + 1] = av[1]; rv2[tid * 3 + 2] = av[2];
    ri2[tid * 3 + 0] = ai[0]; ri2[tid * 3 + 1] = ai[1]; ri2[tid * 3 + 2] = ai[2];
    mv2[tid] = am; mi2[tid] = amI;
  }
  __syncthreads();

  if (tid == 0) {
    float fv[3] = {NEG_INF, NEG_INF, NEG_INF};
    int fi[3] = {IDX_SENT, IDX_SENT, IDX_SENT};
    for (int t = 0; t < 24; ++t) top3_insert(rv2[t], ri2[t], fv, fi);
    float gbv = NEG_INF; int gbi = IDX_SENT;
    for (int t = 0; t < 8; ++t)
      if (mv2[t] > gbv || (mv2[t] == gbv && mi2[t] < gbi)) { gbv = mv2[t]; gbi = mi2[t]; }
    float* c = cand + ((size_t)b * 16 + stripe) * 8;
    c[0] = fv[0]; c[1] = __int_as_float(fi[0]);
    c[2] = fv[1]; c[3] = __int_as_float(fi[1]);
    c[4] = fv[2]; c[5] = __int_as_float(fi[2]);
    c[6] = gbv;   c[7] = __int_as_float(gbi);
  }
}

// ---------------------------------------------------------------------------
// Positive points, phase 2: reduce 16 stripe candidates -> final outputs.
// ---------------------------------------------------------------------------
__global__ void pos_final(const float* __restrict__ cand,
                          float* __restrict__ coords, float* __restrict__ labels) {
  const int b = blockIdx.x;
  if (threadIdx.x != 0) return;
  float fv[3] = {NEG_INF, NEG_INF, NEG_INF};
  int fi[3] = {IDX_SENT, IDX_SENT, IDX_SENT};
  float gbv = NEG_INF; int gbi = IDX_SENT;
  for (int st = 0; st < 16; ++st) {
    const float* c = cand + ((size_t)b * 16 + st) * 8;
    for (int k = 0; k < 3; ++k)
      top3_insert(c[2 * k], __float_as_int(c[2 * k + 1]), fv, fi);
    const float mv = c[6]; const int mi = __float_as_int(c[7]);
    if (mv > gbv || (mv == gbv && mi < gbi)) { gbv = mv; gbi = mi; }
  }
  float* co = coords + (size_t)b * 10;
  float* la = labels + (size_t)b * 5;
  const bool any_peak = (fi[0] != IDX_SENT);
  const int i0 = any_peak ? fi[0] : gbi;
  co[0] = (float)(i0 & 255);
  co[1] = (float)(i0 >> 8);
  la[0] = 1.0f;
  for (int k = 1; k < 3; ++k) {
    const bool valid = (fi[k] != IDX_SENT);
    co[k * 2 + 0] = valid ? (float)(fi[k] & 255) : 0.0f;
    co[k * 2 + 1] = valid ? (float)(fi[k] >> 8) : 0.0f;
    la[k] = valid ? 1.0f : -1.0f;
  }
}

// ---------------------------------------------------------------------------
// Negative points, phase 1: per-64px-chunk count of (heat<0.3) + partial max.
// ---------------------------------------------------------------------------
__global__ __launch_bounds__(256) void neg_count(
    const float* __restrict__ heat, float* __restrict__ ncnt,
    float* __restrict__ pmax) {
  const int blk = blockIdx.x;
  const int b = blk >> 2;
  const int part = blk & 3;
  const int tid = threadIdx.x;
  const int chunk = (part << 8) + tid;
  const float4* s = (const float4*)(heat + (size_t)b * 65536 + chunk * 64);
  int c = 0;
  float mx = NEG_INF;
  for (int i = 0; i < 16; ++i) {
    const float4 v = s[i];
    c += (v.x < 0.3f) + (v.y < 0.3f) + (v.z < 0.3f) + (v.w < 0.3f);
    mx = fmaxf(mx, fmaxf(fmaxf(v.x, v.y), fmaxf(v.z, v.w)));
  }
  ncnt[b * 1024 + chunk] = (float)c;
  __shared__ float mxs[256];
  mxs[tid] = mx;
  __syncthreads();
  if (tid == 0) {
    float gmx = NEG_INF;
    for (int t = 0; t < 256; ++t) gmx = fmaxf(gmx, mxs[t]);
    pmax[blk] = gmx;
  }
}

// ---------------------------------------------------------------------------
// Negative points, phase 2: prefix, PRNG rank select, rescan.
// ---------------------------------------------------------------------------
__global__ __launch_bounds__(256) void neg_select(
    const float* __restrict__ heat, const float* __restrict__ ncnt,
    const float* __restrict__ pmax, float* __restrict__ coords,
    float* __restrict__ labels) {
  const int b = blockIdx.x;
  const int tid = threadIdx.x;
  const float* s = heat + (size_t)b * 65536;
  __shared__ float cnt[1024];
  __shared__ float c256[256];
  __shared__ int pfx[257];
  __shared__ float thr_s;
  __shared__ int fb_s;
  __shared__ int n_s;
  __shared__ int ridx_s[2];

  for (int l = tid; l < 1024; l += 256) cnt[l] = ncnt[b * 1024 + l];
  __syncthreads();
  c256[tid] = cnt[4 * tid] + cnt[4 * tid + 1] + cnt[4 * tid + 2] + cnt[4 * tid + 3];
  __syncthreads();
  if (tid == 0) {
    int tot = 0;
    for (int t = 0; t < 256; ++t) tot += (int)c256[t];
    const float gm = fmaxf(fmaxf(pmax[b * 4], pmax[b * 4 + 1]),
                           fmaxf(pmax[b * 4 + 2], pmax[b * 4 + 3]));
    fb_s = (tot > 0) ? 0 : 1;
    thr_s = (tot > 0) ? 0.3f : gm;
  }
  __syncthreads();
  if (fb_s) {
    const float t2 = thr_s;
    const int base = tid * 256;
    int c = 0;
    for (int i = 0; i < 256; ++i) c += (s[base + i] < t2) ? 1 : 0;
    c256[tid] = (float)c;
    __syncthreads();
  }
  if (tid == 0) {
    int run = 0;
    for (int t = 0; t < 256; ++t) { pfx[t] = run; run += (int)c256[t]; }
    pfx[256] = run;
    const int n = run;
    n_s = n;
    uint32_t k0, k1, a0, a1;
    threefry2x32(0u, 42u, 0u, (uint32_t)b, &k0, &k1);
    threefry2x32(k0, k1, 0u, 0u, &a0, &a1);
    const uint32_t bits0 = a0 ^ a1;
    threefry2x32(k0, k1, 0u, 1u, &a0, &a1);
    const uint32_t bits1 = a0 ^ a1;
    const float u0 = bits_to_uniform(bits0);
    const float u1 = bits_to_uniform(bits1);
    const float nf = (float)(n > 1 ? n : 1);
    int r0 = (int)(u0 * nf);
    int r1 = (int)(u1 * nf);
    const int rmax = (n - 1 > 0) ? n - 1 : 0;
    ridx_s[0] = r0 < rmax ? r0 : rmax;
    ridx_s[1] = r1 < rmax ? r1 : rmax;
    labels[(size_t)b * 5 + 3] = 0.0f;
    labels[(size_t)b * 5 + 4] = 0.0f;
    if (n == 0) {
      coords[(size_t)b * 10 + 6] = 0.0f; coords[(size_t)b * 10 + 7] = 0.0f;
      coords[(size_t)b * 10 + 8] = 0.0f; coords[(size_t)b * 10 + 9] = 0.0f;
    }
  }
  __syncthreads();
  const int n = n_s;
  if (n > 0) {
    const float t2 = thr_s;
    const int p0 = pfx[tid], p1 = pfx[tid + 1];
    const int base = tid * 256;
    for (int j = 0; j < 2; ++j) {
      const int r = ridx_s[j];
      if (r >= p0 && r < p1) {
        int need = r - p0;
        int sel = -1;
        for (int i = 0; i < 256; ++i) {
          if (s[base + i] < t2) {
            if (need == 0) { sel = base + i; break; }
            --need;
          }
        }
        coords[(size_t)b * 10 + 6 + j * 2 + 0] = (float)(sel & 255);
        coords[(size_t)b * 10 + 6 + j * 2 + 1] = (float)(sel >> 8);
      }
    }
  }
}

// ---------------------------------------------------------------------------
extern "C" void kernel_launch(void* const* d_in, const int* in_sizes, int n_in,
                              void* d_out, int out_size, void* d_ws, size_t ws_size,
                              hipStream_t stream) {
  (void)in_sizes; (void)n_in; (void)out_size; (void)ws_size;
  const float* x  = (const float*)d_in[0];
  const float* w1 = (const float*)d_in[1];
  const float* g1 = (const float*)d_in[2];
  const float* b1 = (const float*)d_in[3];
  const float* m1 = (const float*)d_in[4];
  const float* v1 = (const float*)d_in[5];
  const float* w2 = (const float*)d_in[6];
  const float* g2 = (const float*)d_in[7];
  const float* b2 = (const float*)d_in[8];
  const float* m2 = (const float*)d_in[9];
  const float* v2 = (const float*)d_in[10];
  const float* w3 = (const float*)d_in[11];
  const float* b3 = (const float*)d_in[12];

  float* out = (float*)d_out;
  float* heat = out;                         // [32,1,256,256]
  float* coords = out + (size_t)32 * 65536;  // [32,1,5,2]
  float* labels = coords + 320;              // [32,1,5]
  float* logits = labels + 160;              // [32,1,256,256]

  // Transposed weights live in the logits region (overwritten by upsample_k
  // only after both convs have consumed them — stream-ordered, no hazard).
  float* w1t = logits;            // 256*9*64 floats
  float* w2t = logits + 147456;   // 64*9*64 floats

  float* h1 = (float*)d_ws;                        // [32,64,64,64]
  float* h2 = h1 + (size_t)32 * 64 * 64 * 64;      // [32,64,64,64]
  float* lg64 = h1;                                // reuse after conv2
  float* cand = h1 + 131072;
  float* ncnt = h1 + 135168;
  float* pmax = h1 + 167936;

  transpose_w4<<<144, 256, 0, stream>>>(w1, w1t, 2304);
  transpose_w4<<<36, 256, 0, stream>>>(w2, w2t, 576);
  conv3x3_bn_relu<256><<<1024, 256, 0, stream>>>(x, w1t, g1, b1, m1, v1, h1);
  conv3x3_bn_relu<64><<<1024, 256, 0, stream>>>(h1, w2t, g2, b2, m2, v2, h2);
  logits64_k<<<512, 256, 0, stream>>>(h2, w3, b3, lg64);
  upsample_k<<<2048, 256, 0, stream>>>(lg64, logits, heat);
  pos_stripe<<<512, 256, 0, stream>>>(heat, cand);
  pos_final<<<32, 64, 0, stream>>>(cand, coords, labels);
  neg_count<<<128, 256, 0, stream>>>(heat, ncnt, pmax);
  neg_select<<<32, 256, 0, stream>>>(heat, ncnt, pmax, coords, labels);
}

// Round 7
// 802.361 us; speedup vs baseline: 1.2465x; 1.0298x over previous
//
#include <hip/hip_runtime.h>
#include <stdint.h>
#include <math.h>

#define NEG_INF (-__builtin_inff())
#define IDX_SENT 0x7fffffff

// ---------------------------------------------------------------------------
// JAX threefry2x32 (20 rounds), exact replication.
// ---------------------------------------------------------------------------
__device__ __forceinline__ void threefry2x32(uint32_t k0, uint32_t k1,
                                             uint32_t x0, uint32_t x1,
                                             uint32_t* o0, uint32_t* o1) {
  const uint32_t ks2 = k0 ^ k1 ^ 0x1BD11BDAu;
  uint32_t ks[3] = {k0, k1, ks2};
  const int rot[2][4] = {{13, 15, 26, 6}, {17, 29, 16, 24}};
  x0 += ks[0];
  x1 += ks[1];
#pragma unroll
  for (int i = 0; i < 5; ++i) {
#pragma unroll
    for (int j = 0; j < 4; ++j) {
      const int r = rot[i & 1][j];
      x0 += x1;
      x1 = (x1 << r) | (x1 >> (32 - r));
      x1 ^= x0;
    }
    x0 += ks[(i + 1) % 3];
    x1 += ks[(i + 2) % 3] + (uint32_t)(i + 1);
  }
  *o0 = x0;
  *o1 = x1;
}

__device__ __forceinline__ float bits_to_uniform(uint32_t bits) {
  return __uint_as_float((bits >> 9) | 0x3f800000u) - 1.0f;
}

// top3 ordered by (value desc, index asc) — matches jax.lax.top_k tie-break.
__device__ __forceinline__ void top3_insert(float v, int idx, float tv[3], int ti[3]) {
  if ((v > tv[2]) || (v == tv[2] && idx < ti[2])) {
    tv[2] = v; ti[2] = idx;
    if ((tv[2] > tv[1]) || (tv[2] == tv[1] && ti[2] < ti[1])) {
      float fv = tv[1]; int fi = ti[1];
      tv[1] = tv[2]; ti[1] = ti[2];
      tv[2] = fv;     ti[2] = fi;
      if ((tv[1] > tv[0]) || (tv[1] == tv[0] && ti[1] < ti[0])) {
        fv = tv[0]; fi = ti[0];
        tv[0] = tv[1]; ti[0] = ti[1];
        tv[1] = fv;    ti[1] = fi;
      }
    }
  }
}

// ---------------------------------------------------------------------------
// Weight transpose: w[oc][IC][3][3] -> wt[(ic*9+k)][64].
// ---------------------------------------------------------------------------
__global__ __launch_bounds__(256) void transpose_w4(
    const float* __restrict__ w, float* __restrict__ wt, int IC9) {
  const int idx = blockIdx.x * 256 + threadIdx.x;   // qrow*64 + oc
  const int qrow = idx >> 6;
  const int oc = idx & 63;
  const float4 v = *(const float4*)&w[(size_t)oc * IC9 + qrow * 4];
  wt[(size_t)(qrow * 4 + 0) * 64 + oc] = v.x;
  wt[(size_t)(qrow * 4 + 1) * 64 + oc] = v.y;
  wt[(size_t)(qrow * 4 + 2) * 64 + oc] = v.z;
  wt[(size_t)(qrow * 4 + 3) * 64 + oc] = v.w;
}

// ---------------------------------------------------------------------------
// conv3x3 (pad 1) + inference BN + ReLU.  x:[32,IC,64,64] wt:[(IC*9)][64]
// out:[32,64,64,64].
// Grid: 32 batches x 32 tiles (8 rows x 16 cols) = 1024 blocks (4/CU).
// Block: 4 waves; wave w owns ocs [16w,16w+16) (wave-uniform -> SGPR weights
// via s_load, zero vector-memory cost).
// Lane: r = lane&7 (row), lc = (lane>>3)*2 (col pair) -> per 16-lane quarter
// the ds_read_b64 hits 32 distinct banks (conflict-free; the round-6 map
// collided: 2.5e7 conflict cycles).
// Pipeline: register prefetch of next icb + LDS double-buffer, ONE barrier
// per icb — global-load latency overlaps the 4608-cyc compute phase
// (round-6 exposed it at every barrier: VALUBusy 60%).
// Accumulation order per output element: (icb, ic, ky, kx) — identical to
// rounds 1-6 => bit-identical numerics.
// ---------------------------------------------------------------------------
template <int IC>
__global__ __launch_bounds__(256, 4) void conv3x3_bn_relu(
    const float* __restrict__ x, const float* __restrict__ wt,
    const float* __restrict__ g, const float* __restrict__ bb,
    const float* __restrict__ m, const float* __restrict__ vv,
    float* __restrict__ out) {
  __shared__ float xs[2][8][10][20];   // dbuf x 8 ic x 10 halo rows x 20 cols

  const int tid = threadIdx.x;
  const int blk = blockIdx.x;
  const int b = blk >> 5;
  const int tile = blk & 31;
  const int by = (tile >> 2) << 3;   // 8-row tile
  const int bx = (tile & 3) << 4;    // 16-col tile
  const int wv = __builtin_amdgcn_readfirstlane(tid >> 6);  // wave id 0..3
  const int lane = tid & 63;
  const int r = lane & 7;            // output row in tile (bank-friendly map)
  const int lc = (lane >> 3) << 1;   // 0,2,..,14 col base (2 px)
  const int ocbase = wv << 4;        // wave-uniform oc base

  // input staging decomposition (division-free)
  const int sic = tid >> 5;          // 0..7
  const int sc = tid & 31;           // cols 0..17 active
  const int gx = bx + sc - 1;
  const bool cok = (sc < 18) && (gx >= 0) && (gx < 64);

  float acc[2][16];
#pragma unroll
  for (int p = 0; p < 2; ++p)
#pragma unroll
    for (int o = 0; o < 16; ++o) acc[p][o] = 0.0f;

  float pre[10];
  // ---- prologue: load + stage icb=0 into buffer 0 ----
  {
    const float* xp = x + ((size_t)b * IC + sic) * 4096;
#pragma unroll
    for (int rr = 0; rr < 10; ++rr) {
      const int gy = by + rr - 1;
      pre[rr] = 0.0f;
      if (cok && gy >= 0 && gy < 64) pre[rr] = xp[gy * 64 + gx];
    }
#pragma unroll
    for (int rr = 0; rr < 10; ++rr)
      if (sc < 18) xs[0][sic][rr][sc] = pre[rr];
  }
  __syncthreads();

  int cur = 0;
  for (int icb = 0; icb < IC; icb += 8) {
    const bool has_next = (icb + 8) < IC;
    // ---- issue next-icb global loads early (hidden under compute) ----
    if (has_next) {
      const float* xp = x + ((size_t)b * IC + icb + 8 + sic) * 4096;
#pragma unroll
      for (int rr = 0; rr < 10; ++rr) {
        const int gy = by + rr - 1;
        pre[rr] = 0.0f;
        if (cok && gy >= 0 && gy < 64) pre[rr] = xp[gy * 64 + gx];
      }
    }

    // ---- compute from current buffer ----
    const float* wbase = wt + (size_t)icb * 9 * 64 + ocbase;  // uniform
    for (int ic = 0; ic < 8; ++ic) {
#pragma unroll
      for (int ky = 0; ky < 3; ++ky) {
        float xv[4];
        *(float2*)&xv[0] = *(const float2*)&xs[cur][ic][r + ky][lc];
        *(float2*)&xv[2] = *(const float2*)&xs[cur][ic][r + ky][lc + 2];
#pragma unroll
        for (int kx = 0; kx < 3; ++kx) {
          // wave-uniform address -> s_load into SGPRs
          const float4* wp4 = (const float4*)(wbase + (ic * 9 + ky * 3 + kx) * 64);
#pragma unroll
          for (int q = 0; q < 4; ++q) {
            const float4 w4 = wp4[q];
            acc[0][4 * q + 0] = fmaf(xv[kx],     w4.x, acc[0][4 * q + 0]);
            acc[1][4 * q + 0] = fmaf(xv[kx + 1], w4.x, acc[1][4 * q + 0]);
            acc[0][4 * q + 1] = fmaf(xv[kx],     w4.y, acc[0][4 * q + 1]);
            acc[1][4 * q + 1] = fmaf(xv[kx + 1], w4.y, acc[1][4 * q + 1]);
            acc[0][4 * q + 2] = fmaf(xv[kx],     w4.z, acc[0][4 * q + 2]);
            acc[1][4 * q + 2] = fmaf(xv[kx + 1], w4.z, acc[1][4 * q + 2]);
            acc[0][4 * q + 3] = fmaf(xv[kx],     w4.w, acc[0][4 * q + 3]);
            acc[1][4 * q + 3] = fmaf(xv[kx + 1], w4.w, acc[1][4 * q + 3]);
          }
        }
      }
    }

    // ---- write prefetched tile into the other buffer, single barrier ----
    if (has_next) {
#pragma unroll
      for (int rr = 0; rr < 10; ++rr)
        if (sc < 18) xs[cur ^ 1][sic][rr][sc] = pre[rr];
    }
    __syncthreads();
    cur ^= 1;
  }

  // ---- epilogue: BN + ReLU + float2 store ----
#pragma unroll
  for (int o = 0; o < 16; ++o) {
    const int oc = ocbase + o;
    const float sc2 = g[oc] * (1.0f / sqrtf(vv[oc] + 1e-5f));
    const float sh = bb[oc] - m[oc] * sc2;
    float2 v;
    v.x = fmaxf(fmaf(acc[0][o], sc2, sh), 0.0f);
    v.y = fmaxf(fmaf(acc[1][o], sc2, sh), 0.0f);
    *(float2*)&out[(((size_t)b * 64 + oc) * 64 + (by + r)) * 64 + bx + lc] = v;
  }
}

// ---------------------------------------------------------------------------
// 1x1 conv (64->1) + bias into lg64[32][4096].  Grid 32*16 blocks.
// ---------------------------------------------------------------------------
__global__ __launch_bounds__(256) void logits64_k(
    const float* __restrict__ h2, const float* __restrict__ w3,
    const float* __restrict__ b3, float* __restrict__ lg64) {
  const int blk = blockIdx.x;
  const int b = blk >> 4;
  const int p = ((blk & 15) << 8) + threadIdx.x;
  __shared__ float wvv[64];
  if (threadIdx.x < 64) wvv[threadIdx.x] = w3[threadIdx.x];
  __syncthreads();
  float s = b3[0];
  const float* hp = h2 + (size_t)b * 64 * 4096 + p;
  for (int oc = 0; oc < 64; ++oc)
    s = fmaf(hp[(size_t)oc * 4096], wvv[oc], s);
  lg64[b * 4096 + p] = s;
}

// ---------------------------------------------------------------------------
// bilinear 64->256 (half-pixel, edge clamp) + sigmoid.
// ---------------------------------------------------------------------------
__global__ __launch_bounds__(256) void upsample_k(
    const float* __restrict__ lg64, float* __restrict__ logits,
    float* __restrict__ heat) {
  const int blk = blockIdx.x;
  const int b = blk >> 6;
  const int qq = ((blk & 63) << 10) + (threadIdx.x << 2);
  const float* lg = lg64 + b * 4096;
  const int oy = qq >> 8;
  const float sy = (float)oy * 0.25f - 0.375f;
  const float fy = floorf(sy);
  const int y0 = (int)fy;
  const float ty = sy - fy;
  const int y0c = y0 < 0 ? 0 : y0;
  const int y1c = (y0 + 1) > 63 ? 63 : (y0 + 1);
  const float* r0 = lg + y0c * 64;
  const float* r1 = lg + y1c * 64;
  float4 lo, he;
  float* lop = (float*)&lo;
  float* hep = (float*)&he;
#pragma unroll
  for (int j = 0; j < 4; ++j) {
    const int ox = (qq & 255) + j;
    const float sx = (float)ox * 0.25f - 0.375f;
    const float fx = floorf(sx);
    const int x0 = (int)fx;
    const float tx = sx - fx;
    const int x0c = x0 < 0 ? 0 : x0;
    const int x1c = (x0 + 1) > 63 ? 63 : (x0 + 1);
    const float v00 = r0[x0c], v01 = r0[x1c];
    const float v10 = r1[x0c], v11 = r1[x1c];
    const float vtop = v00 + (v01 - v00) * tx;
    const float vbot = v10 + (v11 - v10) * tx;
    const float val = vtop + (vbot - vtop) * ty;
    lop[j] = val;
    hep[j] = 1.0f / (1.0f + expf(-val));
  }
  const size_t o = (size_t)b * 65536 + qq;
  *(float4*)(logits + o) = lo;
  *(float4*)(heat + o) = he;
}

// ---------------------------------------------------------------------------
// Positive points, phase 1: per-stripe 9x9 NMS peak top3 + stripe argmax.
// ---------------------------------------------------------------------------
__global__ __launch_bounds__(256) void pos_stripe(
    const float* __restrict__ heat, float* __restrict__ cand) {
  const int b = blockIdx.x >> 4;
  const int stripe = blockIdx.x & 15;
  const int y0 = stripe << 4;
  const float* s = heat + (size_t)b * 65536;
  const int tid = threadIdx.x;
  __shared__ float sm[24][256];
  __shared__ float rm[24][256];
  __shared__ float rv[256 * 3];
  __shared__ int ri[256 * 3];
  __shared__ float mvv[256];
  __shared__ int mii[256];
  __shared__ float rv2[24];
  __shared__ int ri2[24];
  __shared__ float mv2[8];
  __shared__ int mi2[8];

  for (int l = tid; l < 24 * 256; l += 256) {
    const int rr = l >> 8, xx = l & 255;
    const int gy = y0 - 4 + rr;
    sm[rr][xx] = (gy >= 0 && gy < 256) ? s[gy * 256 + xx] : NEG_INF;
  }
  __syncthreads();
  for (int l = tid; l < 24 * 256; l += 256) {
    const int rr = l >> 8, xx = l & 255;
    const int lo = (xx - 4 < 0) ? 0 : xx - 4;
    const int hi = (xx + 4 > 255) ? 255 : xx + 4;
    float mx = NEG_INF;
    for (int x2 = lo; x2 <= hi; ++x2) mx = fmaxf(mx, sm[rr][x2]);
    rm[rr][xx] = mx;
  }
  __syncthreads();

  float tv[3] = {NEG_INF, NEG_INF, NEG_INF};
  int ti[3] = {IDX_SENT, IDX_SENT, IDX_SENT};
  float bmax = NEG_INF;
  int bidx = IDX_SENT;
  for (int l = tid; l < 16 * 256; l += 256) {
    const int ry = l >> 8, xx = l & 255;
    const int lr = ry + 4;
    const float v = sm[lr][xx];
    float lm = rm[lr - 4][xx];
#pragma unroll
    for (int d = -3; d <= 4; ++d) lm = fmaxf(lm, rm[lr + d][xx]);
    const int gidx = (y0 + ry) * 256 + xx;
    if (v > bmax) { bmax = v; bidx = gidx; }
    if (v == lm && v > 0.1f) top3_insert(v, gidx, tv, ti);
  }

  rv[tid * 3 + 0] = tv[0]; rv[tid * 3 + 1] = tv[1]; rv[tid * 3 + 2] = tv[2];
  ri[tid * 3 + 0] = ti[0]; ri[tid * 3 + 1] = ti[1]; ri[tid * 3 + 2] = ti[2];
  mvv[tid] = bmax; mii[tid] = bidx;
  __syncthreads();

  if (tid < 8) {
    float av[3] = {NEG_INF, NEG_INF, NEG_INF};
    int ai[3] = {IDX_SENT, IDX_SENT, IDX_SENT};
    float am = NEG_INF; int amI = IDX_SENT;
    for (int t = tid * 32; t < tid * 32 + 32; ++t) {
      for (int k = 0; k < 3; ++k) top3_insert(rv[t * 3 + k], ri[t * 3 + k], av, ai);
      if (mvv[t] > am || (mvv[t] == am && mii[t] < amI)) { am = mvv[t]; amI = mii[t]; }
    }
    rv2[tid * 3 + 0] = av[0]; rv2[tid * 3 + 1] = av[1]; rv2[tid * 3 + 2] = av[2];
    ri2[tid * 3 + 0] = ai[0]; ri2[tid * 3 + 1] = ai[1]; ri2[tid * 3 + 2] = ai[2];
    mv2[tid] = am; mi2[tid] = amI;
  }
  __syncthreads();

  if (tid == 0) {
    float fv[3] = {NEG_INF, NEG_INF, NEG_INF};
    int fi[3] = {IDX_SENT, IDX_SENT, IDX_SENT};
    for (int t = 0; t < 24; ++t) top3_insert(rv2[t], ri2[t], fv, fi);
    float gbv = NEG_INF; int gbi = IDX_SENT;
    for (int t = 0; t < 8; ++t)
      if (mv2[t] > gbv || (mv2[t] == gbv && mi2[t] < gbi)) { gbv = mv2[t]; gbi = mi2[t]; }
    float* c = cand + ((size_t)b * 16 + stripe) * 8;
    c[0] = fv[0]; c[1] = __int_as_float(fi[0]);
    c[2] = fv[1]; c[3] = __int_as_float(fi[1]);
    c[4] = fv[2]; c[5] = __int_as_float(fi[2]);
    c[6] = gbv;   c[7] = __int_as_float(gbi);
  }
}

// ---------------------------------------------------------------------------
// Positive points, phase 2: reduce 16 stripe candidates -> final outputs.
// ---------------------------------------------------------------------------
__global__ void pos_final(const float* __restrict__ cand,
                          float* __restrict__ coords, float* __restrict__ labels) {
  const int b = blockIdx.x;
  if (threadIdx.x != 0) return;
  float fv[3] = {NEG_INF, NEG_INF, NEG_INF};
  int fi[3] = {IDX_SENT, IDX_SENT, IDX_SENT};
  float gbv = NEG_INF; int gbi = IDX_SENT;
  for (int st = 0; st < 16; ++st) {
    const float* c = cand + ((size_t)b * 16 + st) * 8;
    for (int k = 0; k < 3; ++k)
      top3_insert(c[2 * k], __float_as_int(c[2 * k + 1]), fv, fi);
    const float mv = c[6]; const int mi = __float_as_int(c[7]);
    if (mv > gbv || (mv == gbv && mi < gbi)) { gbv = mv; gbi = mi; }
  }
  float* co = coords + (size_t)b * 10;
  float* la = labels + (size_t)b * 5;
  const bool any_peak = (fi[0] != IDX_SENT);
  const int i0 = any_peak ? fi[0] : gbi;
  co[0] = (float)(i0 & 255);
  co[1] = (float)(i0 >> 8);
  la[0] = 1.0f;
  for (int k = 1; k < 3; ++k) {
    const bool valid = (fi[k] != IDX_SENT);
    co[k * 2 + 0] = valid ? (float)(fi[k] & 255) : 0.0f;
    co[k * 2 + 1] = valid ? (float)(fi[k] >> 8) : 0.0f;
    la[k] = valid ? 1.0f : -1.0f;
  }
}

// ---------------------------------------------------------------------------
// Negative points, phase 1: per-64px-chunk count of (heat<0.3) + partial max.
// ---------------------------------------------------------------------------
__global__ __launch_bounds__(256) void neg_count(
    const float* __restrict__ heat, float* __restrict__ ncnt,
    float* __restrict__ pmax) {
  const int blk = blockIdx.x;
  const int b = blk >> 2;
  const int part = blk & 3;
  const int tid = threadIdx.x;
  const int chunk = (part << 8) + tid;
  const float4* s = (const float4*)(heat + (size_t)b * 65536 + chunk * 64);
  int c = 0;
  float mx = NEG_INF;
  for (int i = 0; i < 16; ++i) {
    const float4 v = s[i];
    c += (v.x < 0.3f) + (v.y < 0.3f) + (v.z < 0.3f) + (v.w < 0.3f);
    mx = fmaxf(mx, fmaxf(fmaxf(v.x, v.y), fmaxf(v.z, v.w)));
  }
  ncnt[b * 1024 + chunk] = (float)c;
  __shared__ float mxs[256];
  mxs[tid] = mx;
  __syncthreads();
  if (tid == 0) {
    float gmx = NEG_INF;
    for (int t = 0; t < 256; ++t) gmx = fmaxf(gmx, mxs[t]);
    pmax[blk] = gmx;
  }
}

// ---------------------------------------------------------------------------
// Negative points, phase 2: prefix, PRNG rank select, rescan.
// ---------------------------------------------------------------------------
__global__ __launch_bounds__(256) void neg_select(
    const float* __restrict__ heat, const float* __restrict__ ncnt,
    const float* __restrict__ pmax, float* __restrict__ coords,
    float* __restrict__ labels) {
  const int b = blockIdx.x;
  const int tid = threadIdx.x;
  const float* s = heat + (size_t)b * 65536;
  __shared__ float cnt[1024];
  __shared__ float c256[256];
  __shared__ int pfx[257];
  __shared__ float thr_s;
  __shared__ int fb_s;
  __shared__ int n_s;
  __shared__ int ridx_s[2];

  for (int l = tid; l < 1024; l += 256) cnt[l] = ncnt[b * 1024 + l];
  __syncthreads();
  c256[tid] = cnt[4 * tid] + cnt[4 * tid + 1] + cnt[4 * tid + 2] + cnt[4 * tid + 3];
  __syncthreads();
  if (tid == 0) {
    int tot = 0;
    for (int t = 0; t < 256; ++t) tot += (int)c256[t];
    const float gm = fmaxf(fmaxf(pmax[b * 4], pmax[b * 4 + 1]),
                           fmaxf(pmax[b * 4 + 2], pmax[b * 4 + 3]));
    fb_s = (tot > 0) ? 0 : 1;
    thr_s = (tot > 0) ? 0.3f : gm;
  }
  __syncthreads();
  if (fb_s) {
    const float t2 = thr_s;
    const int base = tid * 256;
    int c = 0;
    for (int i = 0; i < 256; ++i) c += (s[base + i] < t2) ? 1 : 0;
    c256[tid] = (float)c;
    __syncthreads();
  }
  if (tid == 0) {
    int run = 0;
    for (int t = 0; t < 256; ++t) { pfx[t] = run; run += (int)c256[t]; }
    pfx[256] = run;
    const int n = run;
    n_s = n;
    uint32_t k0, k1, a0, a1;
    threefry2x32(0u, 42u, 0u, (uint32_t)b, &k0, &k1);
    threefry2x32(k0, k1, 0u, 0u, &a0, &a1);
    const uint32_t bits0 = a0 ^ a1;
    threefry2x32(k0, k1, 0u, 1u, &a0, &a1);
    const uint32_t bits1 = a0 ^ a1;
    const float u0 = bits_to_uniform(bits0);
    const float u1 = bits_to_uniform(bits1);
    const float nf = (float)(n > 1 ? n : 1);
    int r0 = (int)(u0 * nf);
    int r1 = (int)(u1 * nf);
    const int rmax = (n - 1 > 0) ? n - 1 : 0;
    ridx_s[0] = r0 < rmax ? r0 : rmax;
    ridx_s[1] = r1 < rmax ? r1 : rmax;
    labels[(size_t)b * 5 + 3] = 0.0f;
    labels[(size_t)b * 5 + 4] = 0.0f;
    if (n == 0) {
      coords[(size_t)b * 10 + 6] = 0.0f; coords[(size_t)b * 10 + 7] = 0.0f;
      coords[(size_t)b * 10 + 8] = 0.0f; coords[(size_t)b * 10 + 9] = 0.0f;
    }
  }
  __syncthreads();
  const int n = n_s;
  if (n > 0) {
    const float t2 = thr_s;
    const int p0 = pfx[tid], p1 = pfx[tid + 1];
    const int base = tid * 256;
    for (int j = 0; j < 2; ++j) {
      const int r = ridx_s[j];
      if (r >= p0 && r < p1) {
        int need = r - p0;
        int sel = -1;
        for (int i = 0; i < 256; ++i) {
          if (s[base + i] < t2) {
            if (need == 0) { sel = base + i; break; }
            --need;
          }
        }
        coords[(size_t)b * 10 + 6 + j * 2 + 0] = (float)(sel & 255);
        coords[(size_t)b * 10 + 6 + j * 2 + 1] = (float)(sel >> 8);
      }
    }
  }
}

// ---------------------------------------------------------------------------
extern "C" void kernel_launch(void* const* d_in, const int* in_sizes, int n_in,
                              void* d_out, int out_size, void* d_ws, size_t ws_size,
                              hipStream_t stream) {
  (void)in_sizes; (void)n_in; (void)out_size; (void)ws_size;
  const float* x  = (const float*)d_in[0];
  const float* w1 = (const float*)d_in[1];
  const float* g1 = (const float*)d_in[2];
  const float* b1 = (const float*)d_in[3];
  const float* m1 = (const float*)d_in[4];
  const float* v1 = (const float*)d_in[5];
  const float* w2 = (const float*)d_in[6];
  const float* g2 = (const float*)d_in[7];
  const float* b2 = (const float*)d_in[8];
  const float* m2 = (const float*)d_in[9];
  const float* v2 = (const float*)d_in[10];
  const float* w3 = (const float*)d_in[11];
  const float* b3 = (const float*)d_in[12];

  float* out = (float*)d_out;
  float* heat = out;                         // [32,1,256,256]
  float* coords = out + (size_t)32 * 65536;  // [32,1,5,2]
  float* labels = coords + 320;              // [32,1,5]
  float* logits = labels + 160;              // [32,1,256,256]

  // Transposed weights live in the logits region (overwritten by upsample_k
  // only after both convs have consumed them — stream-ordered, no hazard).
  float* w1t = logits;            // 256*9*64 floats
  float* w2t = logits + 147456;   // 64*9*64 floats

  float* h1 = (float*)d_ws;                        // [32,64,64,64]
  float* h2 = h1 + (size_t)32 * 64 * 64 * 64;      // [32,64,64,64]
  float* lg64 = h1;                                // reuse after conv2
  float* cand = h1 + 131072;
  float* ncnt = h1 + 135168;
  float* pmax = h1 + 167936;

  transpose_w4<<<144, 256, 0, stream>>>(w1, w1t, 2304);
  transpose_w4<<<36, 256, 0, stream>>>(w2, w2t, 576);
  conv3x3_bn_relu<256><<<1024, 256, 0, stream>>>(x, w1t, g1, b1, m1, v1, h1);
  conv3x3_bn_relu<64><<<1024, 256, 0, stream>>>(h1, w2t, g2, b2, m2, v2, h2);
  logits64_k<<<512, 256, 0, stream>>>(h2, w3, b3, lg64);
  upsample_k<<<2048, 256, 0, stream>>>(lg64, logits, heat);
  pos_stripe<<<512, 256, 0, stream>>>(heat, cand);
  pos_final<<<32, 64, 0, stream>>>(cand, coords, labels);
  neg_count<<<128, 256, 0, stream>>>(heat, ncnt, pmax);
  neg_select<<<32, 256, 0, stream>>>(heat, ncnt, pmax, coords, labels);
}